// Round 24
// baseline (3183.874 us; speedup 1.0000x reference)
//
#include <hip/hip_runtime.h>

// RNN: B=32, T=2048, E=256, H=256, L=2, f32 in/out, f16 dot core.
// v24 = FULL FUSION of L0-scan + xproj1 + L1-scan into one block per batch.
//   chaser0 kernel: 128 blocks (4/batch): xproj0 = x @ W0x + b0 -> ws.A,
//                   publish xp0done[b][chunk]  (proven v23 pattern)
//   fused kernel: 32 blocks x 768 thr (12 waves, 3 waves/SIMD):
//     group A (waves 0-3):  h0_s   = tanh(xp0[s] + W0h h0_{s-1})   t = s
//     group B (waves 4-7):  xp1_t  = W1x h0_t + b1                 t = s-1
//     group C (waves 8-11): h1_t   = tanh(xp1_t + W1h h1_{t-1})    t = s-2
//   h0 lives in a 3-slot LDS ring; xp1 in a 2-slot f32 ring (stride 66 =>
//   conflict-free); h1 double-buffered. h0/xp1 NEVER touch global (-128MB
//   traffic, no L0->chaser->L1 flags). Per SIMD: 3 waves x 128 independent
//   fdot2 co-issue (~768cy) with overlapping dependency chains — vs v23's
//   1310cy/step single-chain L0. Drain: 2 extra steps for the lag.
// Core (r17-proven, unchanged): thread (jg=ltid>>2, p=ltid&3) partials 4 cols
// {jg+64c} over i-quarter [64p,64p+64): 8 ds_read_b128, 128 fdot2, 2 DPP quad
// butterflies/col, static col select. Weights: 128 packed f16x2 VGPRs (FULL
// unroll + unsigned + KEEPALIVE; launch_bounds(768,3) => 170 VGPR/wave cap,
// demand ~156). Sync: publisher __syncthreads + release store; consumer
// RELAXED poll + one acquire fence per chunk. Per-step barrier is LDS-only.

typedef _Float16 half2_t __attribute__((ext_vector_type(2)));

#define TT 2048
#define BB 32
#define XPB 4
#define CHUNK 64
#define NCHUNK (TT / CHUNK)  // 32

__device__ __forceinline__ unsigned packw(float lo, float hi) {
    half2_t r;
    r.x = (_Float16)lo;
    r.y = (_Float16)hi;
    return __builtin_bit_cast(unsigned, r);
}
#define H2(X) __builtin_bit_cast(half2_t, (X))

#define LDS_BARRIER() asm volatile("s_waitcnt lgkmcnt(0)\n\ts_barrier" ::: "memory")

__device__ __forceinline__ int rload(int* pf) {
    return __hip_atomic_load(pf, __ATOMIC_RELAXED, __HIP_MEMORY_SCOPE_AGENT);
}
__device__ __forceinline__ void astore(int* pf, int v) {
    __hip_atomic_store(pf, v, __ATOMIC_RELEASE, __HIP_MEMORY_SCOPE_AGENT);
}
#define ACQUIRE_FENCE() __builtin_amdgcn_fence(__ATOMIC_ACQUIRE, "agent")

// pin the 128 packed weights in arch VGPRs (r13/r16-proven)
#define KAW8(B)                                                             \
    "+v"(wp[(B)]), "+v"(wp[(B) + 1]), "+v"(wp[(B) + 2]), "+v"(wp[(B) + 3]), \
    "+v"(wp[(B) + 4]), "+v"(wp[(B) + 5]), "+v"(wp[(B) + 6]), "+v"(wp[(B) + 7])
#define KEEPALIVE()                                                  \
    asm volatile("" : KAW8(0), KAW8(8), KAW8(16), KAW8(24));         \
    asm volatile("" : KAW8(32), KAW8(40), KAW8(48), KAW8(56));       \
    asm volatile("" : KAW8(64), KAW8(72), KAW8(80), KAW8(88));       \
    asm volatile("" : KAW8(96), KAW8(104), KAW8(112), KAW8(120));

#define FDOT(H, W_, A) A = __builtin_amdgcn_fdot2(H2(H), H2(W_), A, false)
#define FD4(H, K)               \
    FDOT(H, wp[(K)], ac0);      \
    FDOT(H, wp[32 + (K)], ac1); \
    FDOT(H, wp[64 + (K)], ac2); \
    FDOT(H, wp[96 + (K)], ac3);

// partial dot over this lane's i-quarter for its 4 columns (hbq in scope)
#define DOTS()                                                          \
    float ac0 = 0.f, ac1 = 0.f, ac2 = 0.f, ac3 = 0.f;                   \
    {                                                                   \
        const uint4* hp_ = hbq + 9 * p;                                 \
        uint4 q0 = hp_[0], q1 = hp_[1], q2 = hp_[2], q3 = hp_[3];       \
        uint4 q4 = hp_[4], q5 = hp_[5], q6 = hp_[6], q7 = hp_[7];       \
        FD4(q0.x, 0)  FD4(q0.y, 1)  FD4(q0.z, 2)  FD4(q0.w, 3)         \
        FD4(q1.x, 4)  FD4(q1.y, 5)  FD4(q1.z, 6)  FD4(q1.w, 7)         \
        FD4(q2.x, 8)  FD4(q2.y, 9)  FD4(q2.z, 10) FD4(q2.w, 11)        \
        FD4(q3.x, 12) FD4(q3.y, 13) FD4(q3.z, 14) FD4(q3.w, 15)        \
        FD4(q4.x, 16) FD4(q4.y, 17) FD4(q4.z, 18) FD4(q4.w, 19)        \
        FD4(q5.x, 20) FD4(q5.y, 21) FD4(q5.z, 22) FD4(q5.w, 23)        \
        FD4(q6.x, 24) FD4(q6.y, 25) FD4(q6.z, 26) FD4(q6.w, 27)        \
        FD4(q7.x, 28) FD4(q7.y, 29) FD4(q7.z, 30) FD4(q7.w, 31)        \
    }

// quad butterfly: x = sum over the 4 quad lanes (register-only, exact)
#define BFLY(x)                                                              \
    asm("v_add_f32_dpp %0, %0, %0 quad_perm:[1,0,3,2] row_mask:0xf "         \
        "bank_mask:0xf"                                                      \
        : "+v"(x));                                                          \
    asm("v_add_f32_dpp %0, %0, %0 quad_perm:[2,3,0,1] row_mask:0xf "         \
        "bank_mask:0xf"                                                      \
        : "+v"(x));

// load 128 packed weights (FULL unroll — r15 scratch lesson)
#define LOAD_WP4(Wm, rowbase, p_, jg_)                                       \
    _Pragma("unroll")                                                        \
    for (int c = 0; c < 4; ++c) {                                            \
        _Pragma("unroll")                                                    \
        for (int k = 0; k < 32; ++k) {                                       \
            const int col_ = (jg_) + 64 * c;                                 \
            wp[c * 32 + k] =                                                 \
                packw((Wm)[(size_t)((rowbase) + 64 * (p_) + 2 * k) * 256 +   \
                           col_],                                            \
                      (Wm)[(size_t)((rowbase) + 64 * (p_) + 2 * k + 1) * 256 \
                           + col_]);                                         \
        }                                                                    \
    }

// f16 staging index (quarter stride 72 f16 = 144 B)
__device__ __forceinline__ int sidx_of(int i) {
    return 72 * (i >> 6) + (i & 63);
}

// proj rows (chaser0 + fallback). ALIAS: per-row vmcnt drain for in-place.
template <bool ALIAS>
__device__ __forceinline__ void proj_rows(
    const float* __restrict__ src, float* __restrict__ dst,
    unsigned (&wp)[128], float bj, int nrows, uint4 (*hb)[36], int tid,
    int p, int jg, int col)
{
    _Float16* st0 = reinterpret_cast<_Float16*>(hb[0]);
    _Float16* st1 = reinterpret_cast<_Float16*>(hb[1]);
    const int si = sidx_of(tid);
    st0[si] = (_Float16)src[tid];
    __syncthreads();
    for (int r = 0; r < nrows; ++r) {
        KEEPALIVE()
        _Float16* stn = (r & 1) ? st0 : st1;
        if (r + 1 < nrows) stn[si] = (_Float16)src[(size_t)(r + 1) * 256 + tid];
        const uint4* hbq = hb[r & 1];
        DOTS()
        BFLY(ac0) BFLY(ac1) BFLY(ac2) BFLY(ac3)
        float z = (p == 0) ? ac0 : ((p == 1) ? ac1 : ((p == 2) ? ac2 : ac3));
        dst[(size_t)r * 256 + col] = z + bj;
        if (ALIAS) __syncthreads();
        else LDS_BARRIER();
    }
}

// fallback serial scan (v23 core, no flags)
__device__ __forceinline__ void scan_serial(
    const float* __restrict__ W, const float* __restrict__ h_init,
    const float* __restrict__ xsrc, float* __restrict__ hdst, float* hfinal,
    uint4 (*hb)[36], int tid)
{
    const int p = tid & 3;
    const int jg = tid >> 2;
    const int col = jg + 64 * p;
    unsigned wp[128];
    LOAD_WP4(W, 256, p, jg)
    _Float16* hw0 = reinterpret_cast<_Float16*>(hb[0]);
    _Float16* hw1 = reinterpret_cast<_Float16*>(hb[1]);
    hw0[sidx_of(tid)] = (_Float16)h_init[tid];
    const int wsi = 72 * p + jg;
    __syncthreads();
    float hn = 0.f;
    for (int t = 0; t < TT; ++t) {
        KEEPALIVE()
        const uint4* hbq = hb[t & 1];
        DOTS()
        BFLY(ac0) BFLY(ac1) BFLY(ac2) BFLY(ac3)
        float z = (p == 0) ? ac0 : ((p == 1) ? ac1 : ((p == 2) ? ac2 : ac3));
        z += xsrc[(size_t)t * 256 + col];
        const float e = __expf(2.0f * z);
        hn = 1.0f - 2.0f / (e + 1.0f);
        _Float16* dstw = ((t + 1) & 1) ? hw1 : hw0;
        dstw[wsi] = (_Float16)hn;
        hdst[(size_t)t * 256 + col] = hn;
        LDS_BARRIER();
    }
    if (hfinal != nullptr) hfinal[col] = hn;
}

// ---- chaser0: xproj0 = x @ W0x + b0 -> xpA, publish xp0done. 4/batch. ----
__global__ __launch_bounds__(256, 1) void chaser0_kernel(
    const float* __restrict__ x, const float* __restrict__ W0,
    const float* __restrict__ b0v, float* xpA, int* xp0done)
{
    __shared__ uint4 hb[2][36];
    const int tid = threadIdx.x;
    const int k = blockIdx.x;  // 0..127
    const int b = k >> 2;
    const int quarter = k & 3;
    const int p = tid & 3;
    const int jg = tid >> 2;
    const int col = jg + 64 * p;

    unsigned wp[128];
    LOAD_WP4(W0, 0, p, jg)
    const float bj = b0v[col];

    for (int chunk = quarter; chunk < NCHUNK; chunk += 4) {
        const int tbase = chunk * CHUNK;
        const float* src = x + ((size_t)b * TT + tbase) * 256;
        float* dst = xpA + ((size_t)b * TT + tbase) * 256;
        proj_rows<false>(src, dst, wp, bj, CHUNK, hb, tid, p, jg, col);
        __syncthreads();  // drain vmcnt (dst stores) before release
        if (tid == 0) astore(&xp0done[b * NCHUNK + chunk], 1);
    }
}

// ---- fused: 32 blocks x 768 thr. A=h0 scan, B=xproj1, C=h1 scan. ----
__global__ __launch_bounds__(768, 3) void fused24_kernel(
    const float* __restrict__ xpA, const float* __restrict__ W0,
    const float* __restrict__ W1, const float* __restrict__ b1v,
    const float* __restrict__ h0init, float* __restrict__ out, int* xp0done)
{
    __shared__ __align__(16) _Float16 h0ring[3][288];  // quarter layout/slot
    __shared__ float xp1ring[2][264];                  // stride 66/p-quarter
    __shared__ __align__(16) _Float16 h1buf[2][288];

    const int tid = threadIdx.x;
    const int grp = tid >> 8;  // 0=A, 1=B, 2=C
    const int ltid = tid & 255;
    const int p = ltid & 3;
    const int jg = ltid >> 2;
    const int col = jg + 64 * p;
    const int b = blockIdx.x;

    unsigned wp[128];
    if (grp == 0) {
        LOAD_WP4(W0, 256, p, jg)          // W0h
    } else if (grp == 1) {
        LOAD_WP4(W1, 0, p, jg)            // W1x
    } else {
        LOAD_WP4(W1, 256, p, jg)          // W1h
    }
    const float bj = (grp == 1) ? b1v[col] : 0.f;

    if (grp == 0) h0ring[2][sidx_of(ltid)] = (_Float16)h0init[b * 256 + ltid];
    if (grp == 2)
        h1buf[0][sidx_of(ltid)] = (_Float16)h0init[(size_t)(BB + b) * 256 + ltid];

    const float* xsrc = xpA + (size_t)b * TT * 256;
    float* hdst = out + (size_t)b * TT * 256;
    int* myflags = xp0done + b * NCHUNK;
    __syncthreads();

    float xpc[XPB], xpn[XPB];

    auto STEP = [&](int s, float xp0) {
        KEEPALIVE()
        if (grp == 0) {
            if (s < TT) {
                const uint4* hbq = (const uint4*)h0ring[(s + 2) % 3];
                DOTS()
                BFLY(ac0) BFLY(ac1) BFLY(ac2) BFLY(ac3)
                float z = (p == 0) ? ac0
                        : (p == 1) ? ac1 : ((p == 2) ? ac2 : ac3);
                z += xp0;
                const float e = __expf(2.0f * z);
                const float hn = 1.0f - 2.0f / (e + 1.0f);
                h0ring[s % 3][72 * p + jg] = (_Float16)hn;
            }
        } else if (grp == 1) {
            if (s >= 1 && s <= TT) {
                const int t = s - 1;
                const uint4* hbq = (const uint4*)h0ring[t % 3];
                DOTS()
                BFLY(ac0) BFLY(ac1) BFLY(ac2) BFLY(ac3)
                float z = (p == 0) ? ac0
                        : (p == 1) ? ac1 : ((p == 2) ? ac2 : ac3);
                xp1ring[t & 1][66 * p + jg] = z + bj;
            }
        } else {
            if (s >= 2) {
                const int t = s - 2;
                const float xp = xp1ring[t & 1][66 * p + jg];
                const uint4* hbq = (const uint4*)h1buf[t & 1];
                DOTS()
                BFLY(ac0) BFLY(ac1) BFLY(ac2) BFLY(ac3)
                float z = (p == 0) ? ac0
                        : (p == 1) ? ac1 : ((p == 2) ? ac2 : ac3);
                z += xp;
                const float e = __expf(2.0f * z);
                const float hn = 1.0f - 2.0f / (e + 1.0f);
                h1buf[(t + 1) & 1][72 * p + jg] = (_Float16)hn;
                hdst[(size_t)t * 256 + col] = hn;
                if (t == TT - 1)
                    out[(size_t)BB * TT * 256 + b * 256 + col] = hn;
            }
        }
        LDS_BARRIER();
    };

    for (int chunk = 0; chunk < NCHUNK; ++chunk) {
        const int tbase = chunk * CHUNK;
        if (grp == 0) {
            while (rload(&myflags[chunk]) == 0) __builtin_amdgcn_s_sleep(1);
            ACQUIRE_FENCE();  // one inv per chunk
#pragma unroll
            for (int u = 0; u < XPB; ++u)
                xpc[u] = xsrc[(size_t)(tbase + u) * 256 + col];
        }
        for (int g = 0; g < CHUNK / XPB; ++g) {
            const int s0 = tbase + g * XPB;
            if (grp == 0 && g + 1 < CHUNK / XPB) {
#pragma unroll
                for (int u = 0; u < XPB; ++u)
                    xpn[u] = xsrc[(size_t)(s0 + XPB + u) * 256 + col];
            }
#pragma unroll
            for (int u = 0; u < XPB; ++u) STEP(s0 + u, xpc[u]);
            if (grp == 0 && g + 1 < CHUNK / XPB) {
#pragma unroll
                for (int u = 0; u < XPB; ++u) xpc[u] = xpn[u];
            }
        }
    }
    // drain the 2-step lag (B at t=TT-1, then C at t=TT-1)
    STEP(TT, 0.f);
    STEP(TT + 1, 0.f);
}

// ---- fallback kernels ----
template <bool ALIAS>
__global__ __launch_bounds__(256, 1) void proj24_kernel(
    const float* in, const float* __restrict__ W, const float* __restrict__ bias,
    float* out, int rows_per_wg)
{
    __shared__ uint4 hb[2][36];
    const int tid = threadIdx.x;
    const int p = tid & 3;
    const int jg = tid >> 2;
    const int col = jg + 64 * p;
    unsigned wp[128];
    LOAD_WP4(W, 0, p, jg)
    const float bj = bias[col];
    const size_t r0 = (size_t)blockIdx.x * rows_per_wg;
    proj_rows<ALIAS>(in + r0 * 256, out + r0 * 256, wp, bj, rows_per_wg, hb,
                     tid, p, jg, col);
}

__global__ __launch_bounds__(256, 1) void scan24_kernel(
    const float* __restrict__ W, const float* __restrict__ h_init,
    float* __restrict__ io, float* __restrict__ hfinal)
{
    __shared__ uint4 hb[2][36];
    const int b = blockIdx.x;
    scan_serial(W, h_init + b * 256, io + (size_t)b * TT * 256,
                io + (size_t)b * TT * 256,
                hfinal ? hfinal + b * 256 : nullptr, hb, threadIdx.x);
}

extern "C" void kernel_launch(void* const* d_in, const int* in_sizes, int n_in,
                              void* d_out, int out_size, void* d_ws, size_t ws_size,
                              hipStream_t stream) {
    const float* x  = (const float*)d_in[0];  // [B,T,256]
    const float* h0 = (const float*)d_in[1];  // [2,B,256]
    const float* W0 = (const float*)d_in[2];  // [512,256]
    const float* b0 = (const float*)d_in[3];  // [256]
    const float* W1 = (const float*)d_in[4];  // [512,256]
    const float* b1 = (const float*)d_in[5];  // [256]
    float* out = (float*)d_out;               // [B*T*256] + [B*256]

    const size_t XPA_FLOATS = (size_t)BB * TT * 256;  // 64 MB
    const size_t FLAG_INTS = (size_t)BB * NCHUNK;
    const size_t NEEDED = XPA_FLOATS * 4 + FLAG_INTS * 4;

    if (ws_size >= NEEDED) {
        float* xpA = (float*)d_ws;
        int* flags = (int*)((char*)d_ws + XPA_FLOATS * 4);
        hipMemsetAsync(flags, 0, FLAG_INTS * 4, stream);
        chaser0_kernel<<<4 * BB, 256, 0, stream>>>(x, W0, b0, xpA, flags);
        fused24_kernel<<<BB, 768, 0, stream>>>(xpA, W0, W1, b1, h0, out, flags);
    } else {
        proj24_kernel<true><<<512, 256, 0, stream>>>(x, W0, b0, out, 128);
        scan24_kernel<<<BB, 256, 0, stream>>>(W0, h0, out, nullptr);
        proj24_kernel<true><<<512, 256, 0, stream>>>(out, W1, b1, out, 128);
        scan24_kernel<<<BB, 256, 0, stream>>>(W1, h0 + BB * 256, out,
                                              out + XPA_FLOATS);
    }
}

// Round 25
// 1186.197 us; speedup vs baseline: 2.6841x; 2.6841x over previous
//
#include <hip/hip_runtime.h>

// RNN: B=32, T=2048, E=256, H=256, L=2, f32 in/out, f16 dot core.
// v25 = v23 VERBATIM RESTORE (best measured: 1188us, r23).
// Single mega dispatch, grid 192 (all co-resident, 1 block/CU):
//   bid 0-31    L0 scan: WAIT xp0done[b][chunk] -> steps -> PUBLISH flagL0[b]
//   bid 32-95   xproj1 chasers (2/batch): wait flagL0 -> xproj1 -> chunkdone
//   bid 96-127  L1 scan: wait chunkdone -> d_out + final ht
//   bid 128-191 proj0 chasers (2/batch): xproj0 = x @ W0x + b0 -> ws.A
// Failed-structure ledger (all regressed vs this): r18 TLP (shared-barrier
// lockstep), r19 ILP pairing (regalloc cap), r20 CU co-residency pairing
// (contention; CUs not scarce), r22 8-way i-split (reduce overhead),
// r24 3-wave-group fusion (VGPR budget at 3 waves/SIMD -> AGPR re-parking
// + ring bank conflicts). The scan step is serial-dependency + barrier
// bound at ~1340cy; co-scheduled additions make it worse.
// Scan core (r17-proven): thread (jg=tid>>2, p=tid&3) partials 4 cols
// {jg+64c} over i-quarter [64p,64p+64): 8 ds_read_b128, 128 fdot2, 2 DPP
// quad butterflies/col, static col select. LDS f16 quarter-stride-144B.
// Weights: 128 packed f16x2 VGPRs (FULL unroll + unsigned + KEEPALIVE —
// r15/r16 lessons). Sync (r13-proven): publisher __syncthreads + release
// store; consumer RELAXED poll + one acquire fence per chunk. LDS-only
// scan barrier.

typedef _Float16 half2_t __attribute__((ext_vector_type(2)));

#define TT 2048
#define BB 32
#define XPB 8
#define CHUNK 64
#define NCHUNK (TT / CHUNK)  // 32

__device__ __forceinline__ unsigned packw(float lo, float hi) {
    half2_t r;
    r.x = (_Float16)lo;
    r.y = (_Float16)hi;
    return __builtin_bit_cast(unsigned, r);
}
#define H2(X) __builtin_bit_cast(half2_t, (X))

#define LDS_BARRIER() asm volatile("s_waitcnt lgkmcnt(0)\n\ts_barrier" ::: "memory")

__device__ __forceinline__ int rload(int* pf) {
    return __hip_atomic_load(pf, __ATOMIC_RELAXED, __HIP_MEMORY_SCOPE_AGENT);
}
__device__ __forceinline__ void astore(int* pf, int v) {
    __hip_atomic_store(pf, v, __ATOMIC_RELEASE, __HIP_MEMORY_SCOPE_AGENT);
}
#define ACQUIRE_FENCE() __builtin_amdgcn_fence(__ATOMIC_ACQUIRE, "agent")

// r13/r16-proven keep-alive: pin the 128 packed weights in arch VGPRs
#define KAW8(B)                                                             \
    "+v"(wp[(B)]), "+v"(wp[(B) + 1]), "+v"(wp[(B) + 2]), "+v"(wp[(B) + 3]), \
    "+v"(wp[(B) + 4]), "+v"(wp[(B) + 5]), "+v"(wp[(B) + 6]), "+v"(wp[(B) + 7])
#define KEEPALIVE()                                                  \
    asm volatile("" : KAW8(0), KAW8(8), KAW8(16), KAW8(24));         \
    asm volatile("" : KAW8(32), KAW8(40), KAW8(48), KAW8(56));       \
    asm volatile("" : KAW8(64), KAW8(72), KAW8(80), KAW8(88));       \
    asm volatile("" : KAW8(96), KAW8(104), KAW8(112), KAW8(120));

#define FDOT(H, W_, A) A = __builtin_amdgcn_fdot2(H2(H), H2(W_), A, false)
#define FD4(H, K)               \
    FDOT(H, wp[(K)], ac0);      \
    FDOT(H, wp[32 + (K)], ac1); \
    FDOT(H, wp[64 + (K)], ac2); \
    FDOT(H, wp[96 + (K)], ac3);

// partial dot over this lane's i-quarter for its 4 columns.
#define DOTS()                                                          \
    float ac0 = 0.f, ac1 = 0.f, ac2 = 0.f, ac3 = 0.f;                   \
    {                                                                   \
        const uint4* hp_ = hbq + 9 * p;                                 \
        uint4 q0 = hp_[0], q1 = hp_[1], q2 = hp_[2], q3 = hp_[3];       \
        uint4 q4 = hp_[4], q5 = hp_[5], q6 = hp_[6], q7 = hp_[7];       \
        FD4(q0.x, 0)  FD4(q0.y, 1)  FD4(q0.z, 2)  FD4(q0.w, 3)         \
        FD4(q1.x, 4)  FD4(q1.y, 5)  FD4(q1.z, 6)  FD4(q1.w, 7)         \
        FD4(q2.x, 8)  FD4(q2.y, 9)  FD4(q2.z, 10) FD4(q2.w, 11)        \
        FD4(q3.x, 12) FD4(q3.y, 13) FD4(q3.z, 14) FD4(q3.w, 15)        \
        FD4(q4.x, 16) FD4(q4.y, 17) FD4(q4.z, 18) FD4(q4.w, 19)        \
        FD4(q5.x, 20) FD4(q5.y, 21) FD4(q5.z, 22) FD4(q5.w, 23)        \
        FD4(q6.x, 24) FD4(q6.y, 25) FD4(q6.z, 26) FD4(q6.w, 27)        \
        FD4(q7.x, 28) FD4(q7.y, 29) FD4(q7.z, 30) FD4(q7.w, 31)        \
    }

// quad butterfly: x = sum over the 4 quad lanes (register-only, exact)
#define BFLY(x)                                                              \
    asm("v_add_f32_dpp %0, %0, %0 quad_perm:[1,0,3,2] row_mask:0xf "         \
        "bank_mask:0xf"                                                      \
        : "+v"(x));                                                          \
    asm("v_add_f32_dpp %0, %0, %0 quad_perm:[2,3,0,1] row_mask:0xf "         \
        "bank_mask:0xf"                                                      \
        : "+v"(x));

// load 128 packed weights (FULL unroll — r15 scratch lesson)
#define LOAD_WP4(Wm, rowbase, p_, jg_)                                       \
    _Pragma("unroll")                                                        \
    for (int c = 0; c < 4; ++c) {                                            \
        _Pragma("unroll")                                                    \
        for (int k = 0; k < 32; ++k) {                                       \
            const int col_ = (jg_) + 64 * c;                                 \
            wp[c * 32 + k] =                                                 \
                packw((Wm)[(size_t)((rowbase) + 64 * (p_) + 2 * k) * 256 +   \
                           col_],                                            \
                      (Wm)[(size_t)((rowbase) + 64 * (p_) + 2 * k + 1) * 256 \
                           + col_]);                                         \
        }                                                                    \
    }

// f16 staging index (quarter stride 72 f16 = 144 B)
__device__ __forceinline__ int sidx_of(int i) {
    return 72 * (i >> 6) + (i & 63);
}

// proj rows: dst[r][col] = src[r][:] . W[:256][col] + b[col]
// ALIAS=true: in-place path, per-row full __syncthreads (vmcnt drain).
template <bool ALIAS>
__device__ __forceinline__ void proj_rows(
    const float* __restrict__ src, float* __restrict__ dst,
    unsigned (&wp)[128], float bj, int nrows, uint4 (*hb)[36], int tid,
    int p, int jg, int col)
{
    _Float16* st0 = reinterpret_cast<_Float16*>(hb[0]);
    _Float16* st1 = reinterpret_cast<_Float16*>(hb[1]);
    const int si = sidx_of(tid);
    st0[si] = (_Float16)src[tid];
    __syncthreads();
    for (int r = 0; r < nrows; ++r) {
        KEEPALIVE()
        _Float16* stn = (r & 1) ? st0 : st1;
        if (r + 1 < nrows) stn[si] = (_Float16)src[(size_t)(r + 1) * 256 + tid];
        const uint4* hbq = hb[r & 1];
        DOTS()
        BFLY(ac0) BFLY(ac1) BFLY(ac2) BFLY(ac3)
        float z = (p == 0) ? ac0 : ((p == 1) ? ac1 : ((p == 2) ? ac2 : ac3));
        dst[(size_t)r * 256 + col] = z + bj;
        if (ALIAS) __syncthreads();
        else LDS_BARRIER();
    }
}

// scan core, chunked. WAIT: poll waitflags[chunk] before consuming xp rows.
// PUB: publish pubflag = chunk end after the chunk's h stores drain.
template <bool WAIT, bool PUB>
__device__ __forceinline__ void scan_core(
    const float* __restrict__ W, const float* __restrict__ h_init,
    const float* __restrict__ xsrc, float* __restrict__ hdst, float* hfinal,
    int* pubflag, int* waitflags, uint4 (*hb)[36], int tid)
{
    const int p = tid & 3;
    const int jg = tid >> 2;
    const int col = jg + 64 * p;

    unsigned wp[128];
    LOAD_WP4(W, 256, p, jg)

    _Float16* hw0 = reinterpret_cast<_Float16*>(hb[0]);
    _Float16* hw1 = reinterpret_cast<_Float16*>(hb[1]);
    hw0[sidx_of(tid)] = (_Float16)h_init[tid];
    const int wsi = 72 * p + jg;  // where this lane's column lives

    float xpc[XPB], xpn[XPB], hs[XPB];

    auto step = [&](int t, float xp) -> float {
        KEEPALIVE()
        const uint4* hbq = hb[t & 1];
        DOTS()
        BFLY(ac0) BFLY(ac1) BFLY(ac2) BFLY(ac3)
        float z = (p == 0) ? ac0 : ((p == 1) ? ac1 : ((p == 2) ? ac2 : ac3));
        z += xp;
        const float e = __expf(2.0f * z);
        const float hn = 1.0f - 2.0f / (e + 1.0f);
        _Float16* dstw = ((t + 1) & 1) ? hw1 : hw0;
        dstw[wsi] = (_Float16)hn;
        LDS_BARRIER();
        return hn;
    };

    __syncthreads();
    for (int chunk = 0; chunk < NCHUNK; ++chunk) {
        const int tbase = chunk * CHUNK;
        if (WAIT) {
            while (rload(&waitflags[chunk]) == 0) __builtin_amdgcn_s_sleep(1);
            ACQUIRE_FENCE();  // one inv per chunk
        }
#pragma unroll
        for (int u = 0; u < XPB; ++u)
            xpc[u] = xsrc[(size_t)(tbase + u) * 256 + col];
        for (int g = 0; g < CHUNK / XPB; ++g) {
            const int t0 = tbase + g * XPB;
            if (g + 1 < CHUNK / XPB) {
#pragma unroll
                for (int u = 0; u < XPB; ++u)
                    xpn[u] = xsrc[(size_t)(t0 + XPB + u) * 256 + col];
            }
#pragma unroll
            for (int u = 0; u < XPB; ++u) hs[u] = step(t0 + u, xpc[u]);
#pragma unroll
            for (int u = 0; u < XPB; ++u)
                hdst[(size_t)(t0 + u) * 256 + col] = hs[u];
            if (t0 + XPB == TT && hfinal != nullptr) hfinal[col] = hs[XPB - 1];
            if (g + 1 < CHUNK / XPB) {
#pragma unroll
                for (int u = 0; u < XPB; ++u) xpc[u] = xpn[u];
            }
        }
        if (PUB) {
            __syncthreads();  // drain vmcnt (h stores) before release
            if (tid == 0) astore(pubflag, tbase + CHUNK);
        }
    }
}

// standalone proj (fallback only)
template <bool ALIAS>
__global__ __launch_bounds__(256, 1) void proj25_kernel(
    const float* in, const float* __restrict__ W, const float* __restrict__ bias,
    float* out, int rows_per_wg)
{
    __shared__ uint4 hb[2][36];
    const int tid = threadIdx.x;
    const int p = tid & 3;
    const int jg = tid >> 2;
    const int col = jg + 64 * p;
    unsigned wp[128];
    LOAD_WP4(W, 0, p, jg)
    const float bj = bias[col];
    const size_t r0 = (size_t)blockIdx.x * rows_per_wg;
    proj_rows<ALIAS>(in + r0 * 256, out + r0 * 256, wp, bj, rows_per_wg, hb,
                     tid, p, jg, col);
}

// serial fallback scan (single batch)
__global__ __launch_bounds__(256, 1) void scan25_kernel(
    const float* __restrict__ W, const float* __restrict__ h_init,
    float* __restrict__ io, float* __restrict__ hfinal)
{
    __shared__ uint4 hb[2][36];
    const int b = blockIdx.x;
    scan_core<false, false>(W, h_init + b * 256, io + (size_t)b * TT * 256,
                            io + (size_t)b * TT * 256,
                            hfinal ? hfinal + b * 256 : nullptr, nullptr,
                            nullptr, hb, threadIdx.x);
}

// mega: grid 192 x 256 thr.
__global__ __launch_bounds__(256, 1) void mega25_kernel(
    const float* __restrict__ x, const float* __restrict__ W0,
    const float* __restrict__ b0v, const float* __restrict__ W1,
    const float* __restrict__ b1v, const float* __restrict__ h0init,
    float* xpA, float* out, int* flags)
{
    __shared__ uint4 hb[2][36];
    const int tid = threadIdx.x;
    const int bid = blockIdx.x;
    int* flagL0 = flags;                           // BB x 16 (64B lines)
    int* chunkdone = flags + BB * 16;              // BB x NCHUNK
    int* xp0done = flags + BB * 16 + BB * NCHUNK;  // BB x NCHUNK

    if (bid < BB) {
        // ---- L0 scan: wait xp0done, publish flagL0 ----
        const int b = bid;
        scan_core<true, true>(W0, h0init + b * 256, xpA + (size_t)b * TT * 256,
                              out + (size_t)b * TT * 256, nullptr,
                              &flagL0[b * 16], &xp0done[b * NCHUNK], hb, tid);
    } else if (bid < 3 * BB) {
        // ---- xproj1 chasers (2 per batch) ----
        const int k = bid - BB;  // 0..63
        const int b = k >> 1;
        const int half = k & 1;
        const int p = tid & 3;
        const int jg = tid >> 2;
        const int col = jg + 64 * p;

        unsigned wp[128];
        LOAD_WP4(W1, 0, p, jg)
        const float bj = b1v[col];

        for (int chunk = half; chunk < NCHUNK; chunk += 2) {
            while (rload(&flagL0[b * 16]) < (chunk + 1) * CHUNK)
                __builtin_amdgcn_s_sleep(1);
            ACQUIRE_FENCE();  // one inv per chunk
            const int tbase = chunk * CHUNK;
            const float* src = out + ((size_t)b * TT + tbase) * 256;  // h0 rows
            float* dst = xpA + ((size_t)b * TT + tbase) * 256;        // xproj1
            proj_rows<false>(src, dst, wp, bj, CHUNK, hb, tid, p, jg, col);
            __syncthreads();  // drain vmcnt (dst stores) before release
            if (tid == 0) astore(&chunkdone[b * NCHUNK + chunk], 1);
        }
    } else if (bid < 4 * BB) {
        // ---- L1 scan: wait chunkdone ----
        const int b = bid - 3 * BB;
        scan_core<true, false>(W1, h0init + (size_t)(BB + b) * 256,
                               xpA + (size_t)b * TT * 256,
                               out + (size_t)b * TT * 256,
                               out + (size_t)BB * TT * 256 + b * 256, nullptr,
                               &chunkdone[b * NCHUNK], hb, tid);
    } else {
        // ---- proj0 chasers (2 per batch): x -> xpA, publish xp0done ----
        const int k = bid - 4 * BB;  // 0..63
        const int b = k >> 1;
        const int half = k & 1;
        const int p = tid & 3;
        const int jg = tid >> 2;
        const int col = jg + 64 * p;

        unsigned wp[128];
        LOAD_WP4(W0, 0, p, jg)
        const float bj = b0v[col];

        for (int chunk = half; chunk < NCHUNK; chunk += 2) {
            const int tbase = chunk * CHUNK;
            const float* src = x + ((size_t)b * TT + tbase) * 256;  // input x
            float* dst = xpA + ((size_t)b * TT + tbase) * 256;      // xproj0
            proj_rows<false>(src, dst, wp, bj, CHUNK, hb, tid, p, jg, col);
            __syncthreads();  // drain vmcnt (dst stores) before release
            if (tid == 0) astore(&xp0done[b * NCHUNK + chunk], 1);
        }
    }
}

extern "C" void kernel_launch(void* const* d_in, const int* in_sizes, int n_in,
                              void* d_out, int out_size, void* d_ws, size_t ws_size,
                              hipStream_t stream) {
    const float* x  = (const float*)d_in[0];  // [B,T,256]
    const float* h0 = (const float*)d_in[1];  // [2,B,256]
    const float* W0 = (const float*)d_in[2];  // [512,256]
    const float* b0 = (const float*)d_in[3];  // [256]
    const float* W1 = (const float*)d_in[4];  // [512,256]
    const float* b1 = (const float*)d_in[5];  // [256]
    float* out = (float*)d_out;               // [B*T*256] + [B*256]

    const size_t XPA_FLOATS = (size_t)BB * TT * 256;  // 64 MB
    const size_t FLAG_INTS = (size_t)BB * 16 + 2 * (size_t)BB * NCHUNK;
    const size_t NEEDED = XPA_FLOATS * 4 + FLAG_INTS * 4;

    if (ws_size >= NEEDED) {
        float* xpA = (float*)d_ws;
        int* flags = (int*)((char*)d_ws + XPA_FLOATS * 4);
        hipMemsetAsync(flags, 0, FLAG_INTS * 4, stream);
        mega25_kernel<<<6 * BB, 256, 0, stream>>>(x, W0, b0, W1, b1, h0, xpA,
                                                  out, flags);
    } else {
        proj25_kernel<true><<<512, 256, 0, stream>>>(x, W0, b0, out, 128);
        scan25_kernel<<<BB, 256, 0, stream>>>(W0, h0, out, nullptr);
        proj25_kernel<true><<<512, 256, 0, stream>>>(out, W1, b1, out, 128);
        scan25_kernel<<<BB, 256, 0, stream>>>(W1, h0 + BB * 256, out,
                                              out + XPA_FLOATS);
    }
}